// Round 1
// baseline (131.115 us; speedup 1.0000x reference)
//
#include <hip/hip_runtime.h>

#define BB 4
#define NN 4
#define TT 4
#define AA 128
#define DD 64
#define HWD 36864   // 192*192

__device__ __constant__ int c_ti[4] = {0, 0, 0, 1};
__device__ __constant__ int c_tj[4] = {1, 1, 2, 2};
__device__ __constant__ int c_tk[4] = {2, 3, 3, 3};

// ---------------------------------------------------------------------------
// Pass 1: for each (b,t,a): anchor point = pts[b, ti, anchor_idx], scan image
// tj over all HW points, record min sqrt-dist and argmin index.
// Pass 2: same but anchor point = pts[b, tj, idx_j], scan image tk.
// Shared implementation; SRC selects where the query point comes from.
// ---------------------------------------------------------------------------
template <int PASS>
__global__ __launch_bounds__(256) void
nn_scan_kernel(const float* __restrict__ pts,
               const int* __restrict__ anchor_idx,
               const int* __restrict__ prev_idx,   // pass2: idx_j per (b,t,a)
               float* __restrict__ out_min,
               int* __restrict__ out_idx) {
#pragma clang fp contract(off)
    const int bid = blockIdx.x;              // = (b*TT + t)*AA + a
    const int t = (bid / AA) & 3;
    const int b = bid / (AA * TT);

    int qimg, simg, qpix;
    if (PASS == 1) {
        qimg = c_ti[t];
        simg = c_tj[t];
        qpix = anchor_idx[bid];
    } else {
        qimg = c_tj[t];
        simg = c_tk[t];
        qpix = prev_idx[bid];
    }

    const float* qp = pts + ((long)(b * NN + qimg) * HWD + qpix) * 3;
    const float qx = qp[0], qy = qp[1], qz = qp[2];
    const float sq = qx * qx + qy * qy + qz * qz;

    const float* sp = pts + (long)(b * NN + simg) * HWD * 3;

    float best = 3.4e38f;
    int besti = 0;
    for (int p = threadIdx.x; p < HWD; p += 256) {
        const float px = sp[p * 3 + 0];
        const float py = sp[p * 3 + 1];
        const float pz = sp[p * 3 + 2];
        const float s2 = px * px + py * py + pz * pz;
        const float dot = qx * px + qy * py + qz * pz;
        const float d2 = (sq + s2) - 2.0f * dot;
        if (d2 < best) { best = d2; besti = p; }   // ascending p -> first occurrence
    }

    __shared__ float sd[256];
    __shared__ int si[256];
    sd[threadIdx.x] = best;
    si[threadIdx.x] = besti;
    __syncthreads();
    for (int s = 128; s > 0; s >>= 1) {
        if (threadIdx.x < (unsigned)s) {
            const float od = sd[threadIdx.x + s];
            const int oi = si[threadIdx.x + s];
            if (od < sd[threadIdx.x] ||
                (od == sd[threadIdx.x] && oi < si[threadIdx.x])) {
                sd[threadIdx.x] = od;
                si[threadIdx.x] = oi;
            }
        }
        __syncthreads();
    }
    if (threadIdx.x == 0) {
        out_min[bid] = sqrtf(fmaxf(sd[0], 0.0f));
        out_idx[bid] = si[0];
    }
}

// ---------------------------------------------------------------------------
// Pass 3: per (b,t) block, 128 threads (one per anchor).
//   - dki: dist(pkc[a], anchor_pts[a']) min/argmin over a' in [0,128)
//   - feat_ret = feats[b, ti, idx_i_ret(!)]  (raw pixel index 0..127, as ref)
//   - se = || normalize(feat_ret) - normalize(anchor_fts) ||^2
//   - reduce cnt / sum(se*valid) -> loss_bt, batch_ok
// ---------------------------------------------------------------------------
__global__ __launch_bounds__(128) void
pass3_kernel(const float* __restrict__ pts,
             const float* __restrict__ feats,
             const int* __restrict__ anchor_idx,
             const float* __restrict__ min_ij,
             const float* __restrict__ min_jk,
             const int* __restrict__ idx_k,
             float* __restrict__ loss_bt,
             float* __restrict__ batch_ok) {
#pragma clang fp contract(off)
    const int bt = blockIdx.x;          // b*TT + t
    const int t = bt & 3;
    const int b = bt >> 2;
    const int i = c_ti[t];
    const int k = c_tk[t];
    const int a = threadIdx.x;
    const int g = bt * AA + a;

    const int ai = anchor_idx[g];
    const float* ap = pts + ((long)(b * NN + i) * HWD + ai) * 3;

    __shared__ float aps[AA][3];
    aps[a][0] = ap[0];
    aps[a][1] = ap[1];
    aps[a][2] = ap[2];

    const int ik = idx_k[g];
    const float* kp = pts + ((long)(b * NN + k) * HWD + ik) * 3;
    const float kx = kp[0], ky = kp[1], kz = kp[2];
    const float sk = kx * kx + ky * ky + kz * kz;
    __syncthreads();

    float best = 3.4e38f;
    int besti = 0;
    for (int a2 = 0; a2 < AA; ++a2) {
        const float qx = aps[a2][0], qy = aps[a2][1], qz = aps[a2][2];
        const float s2 = qx * qx + qy * qy + qz * qz;
        const float dot = kx * qx + ky * qy + kz * qz;
        const float d2 = (sk + s2) - 2.0f * dot;
        if (d2 < best) { best = d2; besti = a2; }
    }
    const float min_ki = sqrtf(fmaxf(best, 0.0f));

    const int valid =
        (min_ij[g] < 0.3f) && (min_jk[g] < 0.3f) && (min_ki < 0.3f);

    // feat_ret: NOTE reference indexes fi's HW axis with argmin over anchors
    // (value in [0,128)) -> raw pixel index. Replicated exactly.
    const float* fr = feats + ((long)(b * NN + i) * HWD + besti) * DD;
    const float* fa = feats + ((long)(b * NN + i) * HWD + ai) * DD;

    float snr = 0.0f, sna = 0.0f;
    for (int d = 0; d < DD; ++d) {
        const float x = fr[d];
        snr += x * x;
    }
    for (int d = 0; d < DD; ++d) {
        const float y = fa[d];
        sna += y * y;
    }
    const float nr = fmaxf(sqrtf(snr), 1e-12f);
    const float na = fmaxf(sqrtf(sna), 1e-12f);
    float se = 0.0f;
    for (int d = 0; d < DD; ++d) {
        const float x = fr[d] / nr - fa[d] / na;
        se += x * x;
    }

    __shared__ float scnt[AA];
    __shared__ float sse[AA];
    scnt[a] = (float)valid;
    sse[a] = valid ? se : 0.0f;
    __syncthreads();
    for (int s = 64; s > 0; s >>= 1) {
        if (a < s) {
            scnt[a] += scnt[a + s];
            sse[a] += sse[a + s];
        }
        __syncthreads();
    }
    if (a == 0) {
        const float cnt = scnt[0];
        loss_bt[bt] = (cnt > 0.0f) ? sse[0] / (fmaxf(cnt, 1.0f) * (float)DD)
                                   : 0.0f;
        batch_ok[bt] = (cnt >= 5.0f) ? 1.0f : 0.0f;
    }
}

// ---------------------------------------------------------------------------
// Pass 4: final scalar. 16 values -> 1.
// ---------------------------------------------------------------------------
__global__ void final_kernel(const float* __restrict__ loss_bt,
                             const float* __restrict__ batch_ok,
                             float* __restrict__ out) {
    if (threadIdx.x == 0 && blockIdx.x == 0) {
        float s = 0.0f;
        for (int t = 0; t < TT; ++t) {
            float tc = 0.0f, sl = 0.0f;
            for (int b = 0; b < BB; ++b) {
                const float ok = batch_ok[b * TT + t];
                tc += ok;
                sl += loss_bt[b * TT + t] * ok;
            }
            s += (tc > 0.0f) ? sl / fmaxf(tc, 1.0f) : 0.0f;
        }
        out[0] = s / (float)TT;
    }
}

extern "C" void kernel_launch(void* const* d_in, const int* in_sizes, int n_in,
                              void* d_out, int out_size, void* d_ws,
                              size_t ws_size, hipStream_t stream) {
    const float* feats = (const float*)d_in[0];   // (B,N,H,W,D) f32
    const float* pts = (const float*)d_in[1];     // (B,N,H,W,3) f32
    const int* anchor = (const int*)d_in[2];      // (B,T,A) i32
    float* out = (float*)d_out;

    float* ws = (float*)d_ws;
    float* min_ij = ws;                 // 2048 f32
    int* idx_j = (int*)(ws + 2048);     // 2048 i32
    float* min_jk = ws + 4096;          // 2048 f32
    int* idx_k = (int*)(ws + 6144);     // 2048 i32
    float* loss_bt = ws + 8192;         // 16 f32
    float* batch_ok = ws + 8208;        // 16 f32

    const int nblk = BB * TT * AA;      // 2048

    nn_scan_kernel<1><<<nblk, 256, 0, stream>>>(pts, anchor, nullptr, min_ij,
                                                idx_j);
    nn_scan_kernel<2><<<nblk, 256, 0, stream>>>(pts, anchor, idx_j, min_jk,
                                                idx_k);
    pass3_kernel<<<BB * TT, 128, 0, stream>>>(pts, feats, anchor, min_ij,
                                              min_jk, idx_k, loss_bt,
                                              batch_ok);
    final_kernel<<<1, 64, 0, stream>>>(loss_bt, batch_ok, out);
}

// Round 2
// 103.640 us; speedup vs baseline: 1.2651x; 1.2651x over previous
//
#include <hip/hip_runtime.h>

#define BB 4
#define NN 4
#define TT 4
#define AA 128
#define DD 64
#define HWD 36864        // 192*192
#define NPTS (BB * NN * HWD)   // 589824
#define NG (BB * TT * AA)      // 2048
#define CHUNKS 128
#define CPTS (HWD / CHUNKS)    // 288

__device__ __constant__ int c_ti[4] = {0, 0, 0, 1};
__device__ __constant__ int c_tj[4] = {1, 1, 2, 2};
__device__ __constant__ int c_tk[4] = {2, 3, 3, 3};

// ---------------------------------------------------------------------------
// Pack pointmaps into float4 (x, y, z, |p|^2).
// ---------------------------------------------------------------------------
__global__ __launch_bounds__(256) void
pack_kernel(const float* __restrict__ pts, float4* __restrict__ pk4) {
#pragma clang fp contract(off)
    const int idx = blockIdx.x * 256 + threadIdx.x;
    if (idx < NPTS) {
        const float x = pts[idx * 3 + 0];
        const float y = pts[idx * 3 + 1];
        const float z = pts[idx * 3 + 2];
        pk4[idx] = make_float4(x, y, z, x * x + y * y + z * z);
    }
}

// ---------------------------------------------------------------------------
// NN scan: block = one (b,t) x one point-chunk; 128 threads = 128 queries.
// All lanes read the SAME point each step (uniform address, broadcast).
// Key = s2 - 2*dot  (order-equivalent to d2 = sq + s2 - 2*dot).
// PASS 1: query = anchor point of image ti, scan image tj.
// PASS 2: query = pts_j[idx_j],           scan image tk.
// Writes per-chunk partial (key, global argmin index).
// ---------------------------------------------------------------------------
template <int PASS>
__global__ __launch_bounds__(128) void
nn_scan_kernel(const float4* __restrict__ pk4,
               const int* __restrict__ anchor_idx,
               const int* __restrict__ prev_idx,
               float* __restrict__ pkey,
               int* __restrict__ pidx) {
    const int chunk = blockIdx.x % CHUNKS;
    const int bt = blockIdx.x / CHUNKS;
    const int t = bt & 3;
    const int b = bt >> 2;
    const int a = threadIdx.x;
    const int g = bt * AA + a;

    int qimg, simg, qpix;
    if (PASS == 1) {
        qimg = c_ti[t];
        simg = c_tj[t];
        qpix = anchor_idx[g];
    } else {
        qimg = c_tj[t];
        simg = c_tk[t];
        qpix = prev_idx[g];
    }

    const float4 q = pk4[(b * NN + qimg) * HWD + qpix];
    const float m2x = -2.0f * q.x;
    const float m2y = -2.0f * q.y;
    const float m2z = -2.0f * q.z;

    const float4* sp = pk4 + (b * NN + simg) * HWD + chunk * CPTS;

    float best = 3.4e38f;
    int besti = 0;
#pragma unroll 4
    for (int p = 0; p < CPTS; ++p) {
        const float4 P = sp[p];
        const float key = fmaf(P.x, m2x, fmaf(P.y, m2y, fmaf(P.z, m2z, P.w)));
        if (key < best) { best = key; besti = p; }   // ascending -> first occ
    }

    pkey[chunk * NG + g] = best;
    pidx[chunk * NG + g] = chunk * CPTS + besti;
}

// ---------------------------------------------------------------------------
// Combine: block = one g (b,t,a); 128 threads = 128 chunk partials.
// Tie-break to smaller global index (== earlier chunk) => first occurrence.
// min = sqrt(max(key + |q|^2, 0)).
// ---------------------------------------------------------------------------
template <int PASS>
__global__ __launch_bounds__(128) void
combine_kernel(const float4* __restrict__ pk4,
               const int* __restrict__ anchor_idx,
               const int* __restrict__ prev_idx,
               const float* __restrict__ pkey,
               const int* __restrict__ pidx,
               float* __restrict__ out_min,
               int* __restrict__ out_idx) {
    const int g = blockIdx.x;
    const int c = threadIdx.x;

    __shared__ float sk[128];
    __shared__ int si[128];
    sk[c] = pkey[c * NG + g];
    si[c] = pidx[c * NG + g];
    __syncthreads();
    for (int s = 64; s > 0; s >>= 1) {
        if (c < s) {
            const float ok = sk[c + s];
            const int oi = si[c + s];
            if (ok < sk[c] || (ok == sk[c] && oi < si[c])) {
                sk[c] = ok;
                si[c] = oi;
            }
        }
        __syncthreads();
    }
    if (c == 0) {
        const int t = (g / AA) & 3;
        const int b = g / (AA * TT);
        const int qimg = (PASS == 1) ? c_ti[t] : c_tj[t];
        const int qpix = (PASS == 1) ? anchor_idx[g] : prev_idx[g];
        const float4 q = pk4[(b * NN + qimg) * HWD + qpix];
        out_min[g] = sqrtf(fmaxf(sk[0] + q.w, 0.0f));
        out_idx[g] = si[0];
    }
}

// ---------------------------------------------------------------------------
// Pass 3: per (b,t) block, 128 threads (one per anchor).
//   - dki: dist(pkc[a], anchor_pts[a']) min/argmin over a' in [0,128)
//   - feat_ret = feats[b, ti, idx_i_ret(!)]  (raw pixel index 0..127, as ref)
//   - se = || normalize(feat_ret) - normalize(anchor_fts) ||^2
//   - reduce cnt / sum(se*valid) -> loss_bt, batch_ok
// ---------------------------------------------------------------------------
__global__ __launch_bounds__(128) void
pass3_kernel(const float* __restrict__ pts,
             const float* __restrict__ feats,
             const int* __restrict__ anchor_idx,
             const float* __restrict__ min_ij,
             const float* __restrict__ min_jk,
             const int* __restrict__ idx_k,
             float* __restrict__ loss_bt,
             float* __restrict__ batch_ok) {
#pragma clang fp contract(off)
    const int bt = blockIdx.x;
    const int t = bt & 3;
    const int b = bt >> 2;
    const int i = c_ti[t];
    const int k = c_tk[t];
    const int a = threadIdx.x;
    const int g = bt * AA + a;

    const int ai = anchor_idx[g];
    const float* ap = pts + ((long)(b * NN + i) * HWD + ai) * 3;

    __shared__ float aps[AA][3];
    aps[a][0] = ap[0];
    aps[a][1] = ap[1];
    aps[a][2] = ap[2];

    const int ik = idx_k[g];
    const float* kp = pts + ((long)(b * NN + k) * HWD + ik) * 3;
    const float kx = kp[0], ky = kp[1], kz = kp[2];
    const float sk = kx * kx + ky * ky + kz * kz;
    __syncthreads();

    float best = 3.4e38f;
    int besti = 0;
    for (int a2 = 0; a2 < AA; ++a2) {
        const float qx = aps[a2][0], qy = aps[a2][1], qz = aps[a2][2];
        const float s2 = qx * qx + qy * qy + qz * qz;
        const float dot = kx * qx + ky * qy + kz * qz;
        const float d2 = (sk + s2) - 2.0f * dot;
        if (d2 < best) { best = d2; besti = a2; }
    }
    const float min_ki = sqrtf(fmaxf(best, 0.0f));

    const int valid =
        (min_ij[g] < 0.3f) && (min_jk[g] < 0.3f) && (min_ki < 0.3f);

    const float* fr = feats + ((long)(b * NN + i) * HWD + besti) * DD;
    const float* fa = feats + ((long)(b * NN + i) * HWD + ai) * DD;

    float snr = 0.0f, sna = 0.0f;
    for (int d = 0; d < DD; ++d) {
        const float x = fr[d];
        snr += x * x;
    }
    for (int d = 0; d < DD; ++d) {
        const float y = fa[d];
        sna += y * y;
    }
    const float nr = fmaxf(sqrtf(snr), 1e-12f);
    const float na = fmaxf(sqrtf(sna), 1e-12f);
    float se = 0.0f;
    for (int d = 0; d < DD; ++d) {
        const float x = fr[d] / nr - fa[d] / na;
        se += x * x;
    }

    __shared__ float scnt[AA];
    __shared__ float sse[AA];
    scnt[a] = (float)valid;
    sse[a] = valid ? se : 0.0f;
    __syncthreads();
    for (int s = 64; s > 0; s >>= 1) {
        if (a < s) {
            scnt[a] += scnt[a + s];
            sse[a] += sse[a + s];
        }
        __syncthreads();
    }
    if (a == 0) {
        const float cnt = scnt[0];
        loss_bt[bt] = (cnt > 0.0f) ? sse[0] / (fmaxf(cnt, 1.0f) * (float)DD)
                                   : 0.0f;
        batch_ok[bt] = (cnt >= 5.0f) ? 1.0f : 0.0f;
    }
}

__global__ void final_kernel(const float* __restrict__ loss_bt,
                             const float* __restrict__ batch_ok,
                             float* __restrict__ out) {
    if (threadIdx.x == 0 && blockIdx.x == 0) {
        float s = 0.0f;
        for (int t = 0; t < TT; ++t) {
            float tc = 0.0f, sl = 0.0f;
            for (int b = 0; b < BB; ++b) {
                const float ok = batch_ok[b * TT + t];
                tc += ok;
                sl += loss_bt[b * TT + t] * ok;
            }
            s += (tc > 0.0f) ? sl / fmaxf(tc, 1.0f) : 0.0f;
        }
        out[0] = s / (float)TT;
    }
}

extern "C" void kernel_launch(void* const* d_in, const int* in_sizes, int n_in,
                              void* d_out, int out_size, void* d_ws,
                              size_t ws_size, hipStream_t stream) {
    const float* feats = (const float*)d_in[0];   // (B,N,H,W,D) f32
    const float* pts = (const float*)d_in[1];     // (B,N,H,W,3) f32
    const int* anchor = (const int*)d_in[2];      // (B,T,A) i32
    float* out = (float*)d_out;

    float* ws = (float*)d_ws;
    float4* pk4 = (float4*)ws;                    // NPTS float4  (9.4 MB)
    float* pkey = ws + NPTS * 4;                  // CHUNKS*NG f32 (1 MB)
    int* pidx = (int*)(pkey + CHUNKS * NG);       // CHUNKS*NG i32
    float* min_ij = pkey + 2 * CHUNKS * NG;       // NG f32
    int* idx_j = (int*)(min_ij + NG);
    float* min_jk = min_ij + 2 * NG;
    int* idx_k = (int*)(min_ij + 3 * NG);
    float* loss_bt = min_ij + 4 * NG;             // 16 f32
    float* batch_ok = loss_bt + 16;               // 16 f32

    pack_kernel<<<(NPTS + 255) / 256, 256, 0, stream>>>(pts, pk4);

    nn_scan_kernel<1><<<BB * TT * CHUNKS, 128, 0, stream>>>(pk4, anchor,
                                                            nullptr, pkey,
                                                            pidx);
    combine_kernel<1><<<NG, 128, 0, stream>>>(pk4, anchor, nullptr, pkey, pidx,
                                              min_ij, idx_j);

    nn_scan_kernel<2><<<BB * TT * CHUNKS, 128, 0, stream>>>(pk4, anchor, idx_j,
                                                            pkey, pidx);
    combine_kernel<2><<<NG, 128, 0, stream>>>(pk4, anchor, idx_j, pkey, pidx,
                                              min_jk, idx_k);

    pass3_kernel<<<BB * TT, 128, 0, stream>>>(pts, feats, anchor, min_ij,
                                              min_jk, idx_k, loss_bt,
                                              batch_ok);
    final_kernel<<<1, 64, 0, stream>>>(loss_bt, batch_ok, out);
}